// Round 9
// baseline (219.914 us; speedup 1.0000x reference)
//
#include <hip/hip_runtime.h>
#include <hip/hip_fp16.h>

// InteractionBlock, MI355X, round 9.
//
// y = out @ W3 + gathersum(out) @ (W2@W3) + (b2@W3 + b3)
// R8 post-mortem: prep's sort was concentrated in the first 196 of 12501
// blocks (grid tail at ~1% occupancy) AND the 32-int bitonic spilled to
// scratch at VGPR_Count=64 -> 105us of near-idle machine. R9 splits prep:
//   pack_kernel: fp16 row pack + weight prep (memory-bound, ~10us)
//   sort_kernel: 782 blocks x 64 threads (one wave each, spread over all
//     CUs), __launch_bounds__(64,1) -> VGPR budget 512, bitonic network
//     provably in registers; transposed writes stay coalesced (64
//     consecutive dwords per wave per rank).
// fused_kernel unchanged from R7/R8: slot-major gather over per-g sorted,
// transposed indices (s_load_dwordx16 -> 16 loads in flight/wave; lockstep
// quantile sweep keeps per-XCD L2 hot), MFMA 16x16x32 f16 epilogue.

constexpr int A   = 64;    // ao_vals
constexpr int K   = 32;    // neighbors
constexpr int GPW = 16;    // grid points per wave
constexpr int GPB = 64;    // grid points per block (4 waves)
constexpr int XS  = 136;   // X row stride in halves (16B rows, 4-bank shift)

typedef _Float16 f16x8 __attribute__((ext_vector_type(8)));
typedef float    f32x4 __attribute__((ext_vector_type(4)));

// ---- pack kernel: fp16 row pack + weight prep ----
// thread d: pack out (fp32 [2][G][64]) -> packed ([G+1][64] half2);
//   dword c of row g: c<32 -> batch0 pair (2c,2c+1), else batch1; row G = 0.
// last block additionally: WTg[n][0..127] = (half) concat(W2@W3, W3) col n;
//   bb = b2@W3 + b3 (fp32).
__global__ void pack_kernel(const float2* __restrict__ out2,
                            const float* __restrict__ W2, const float* __restrict__ b2,
                            const float* __restrict__ W3, const float* __restrict__ b3,
                            __half2* __restrict__ packed, __half* __restrict__ WTg,
                            float* __restrict__ bb, const int G, const int nBlocks) {
  const int tid = threadIdx.x;
  const int d = blockIdx.x * 256 + tid;

  if (d < (G + 1) * 64) {
    const int g = d >> 6, c = d & 63;
    float2 v = make_float2(0.f, 0.f);
    if (g < G) v = out2[(size_t)(c >> 5) * (G * 32) + (size_t)g * 32 + (c & 31)];
    packed[d] = __floats2half2_rn(v.x, v.y);
  }

  if (blockIdx.x == nBlocks - 1) {
#pragma unroll 1
    for (int e = tid; e < A * A; e += 256) {
      const int n = e >> 6, k = e & 63;
      float acc = 0.f;
#pragma unroll
      for (int q = 0; q < A; ++q) acc = fmaf(W2[k * A + q], W3[q * A + n], acc);
      WTg[n * 128 + k]     = __float2half(acc);            // W23 (k = 0..63)
      WTg[n * 128 + A + k] = __float2half(W3[k * A + n]);  // W3  (k = 64..127)
    }
    if (tid < A) {
      float b = b3[tid];
#pragma unroll
      for (int q = 0; q < A; ++q) b = fmaf(b2[q], W3[q * A + tid], b);
      bb[tid] = b;
    }
  }
}

// ---- sort kernel: one wave per block, one g per thread ----
// 64-thread blocks spread the 50000 sorts over all CUs (~3 waves/CU);
// launch_bounds(64,1) -> VGPR budget 512: the 32-int bitonic network and
// its staging stay in registers (R8's spill at VGPR=64 was the killer).
// Transposed write: at rank k, the wave's 64 threads write 64 consecutive
// dwords of row k -> coalesced.
__global__ __launch_bounds__(64, 1) void sort_kernel(
    const int* __restrict__ nbr, int* __restrict__ sortedT,
    const int G, const int Gpad) {
  const int g = blockIdx.x * 64 + threadIdx.x;
  if (g >= G) return;

  int v[K];
  const int4* np = (const int4*)(nbr + (size_t)g * K);
#pragma unroll
  for (int q = 0; q < 8; ++q) {
    const int4 t4 = np[q];
    v[4 * q] = t4.x; v[4 * q + 1] = t4.y; v[4 * q + 2] = t4.z; v[4 * q + 3] = t4.w;
  }
  // Bitonic network, ascending; static indexing -> registers only.
#pragma unroll
  for (int sz = 2; sz <= K; sz <<= 1) {
#pragma unroll
    for (int st = sz >> 1; st >= 1; st >>= 1) {
#pragma unroll
      for (int i = 0; i < K; ++i) {
        const int j = i ^ st;
        if (j > i) {
          const bool up = (i & sz) == 0;
          const int a = v[i], b = v[j];
          const int lo = a < b ? a : b, hi = a < b ? b : a;
          v[i] = up ? lo : hi;
          v[j] = up ? hi : lo;
        }
      }
    }
  }
#pragma unroll
  for (int k = 0; k < K; ++k)
    sortedT[(size_t)k * Gpad + g] = v[k];
}

// ---- fused kernel: slot-major SMEM-indexed gather + MFMA epilogue ----
// (unchanged from R7/R8)
// LDS X = 128 x 136 halves = 34.8 KB -> 4 blocks/CU; grid 782 -> one
// co-resident generation, near-lockstep k sweep over address quantiles.
__global__ __launch_bounds__(256, 4) void fused_kernel(
    const __half2* __restrict__ packed, const int* __restrict__ sortedT,
    const __half* __restrict__ WTg, const float* __restrict__ bb,
    float* __restrict__ y, const int G, const int Gpad) {
  __shared__ __half X[128 * XS];   // row = batch*64 + gl; cols [m(64)|o(64)]

  const int tid = threadIdx.x;
  const int lane = tid & 63;
  const int w = __builtin_amdgcn_readfirstlane(tid >> 6);  // uniform wave id
  const int g0w = blockIdx.x * GPB + w * GPW;              // wave's first g

  const __half2 z = __floats2half2_rn(0.f, 0.f);
  __half2 acc[GPW];
#pragma unroll
  for (int gi = 0; gi < GPW; ++gi) acc[gi] = z;

  // G % GPW == 0, so each wave's 16 g's are all-valid or all-invalid.
  if (g0w < G) {
    // Slot-major gather. ip is wave-uniform + contiguous -> s_load_dwordx16;
    // 16 independent loads in flight per slot, 16 fp16 acc chains.
#pragma unroll 2
    for (int k = 0; k < K; ++k) {
      const int* ip = sortedT + (size_t)k * Gpad + g0w;    // uniform pointer
#pragma unroll
      for (int gi = 0; gi < GPW; ++gi) {
        const int j = ip[gi];                              // SGPR via s_load
        acc[gi] = __hadd2(acc[gi], packed[(size_t)j * 64 + lane]);
      }
    }

    // Stage X: message (cols 0..63) + residual row (cols 64..127).
    const int e2 = 2 * (lane & 31);
    const int rb = (lane >> 5) * 64;                       // batch row base
#pragma unroll
    for (int gi = 0; gi < GPW; ++gi) {
      const int row = rb + w * GPW + gi;
      *(__half2*)&X[row * XS + e2] = acc[gi];
      *(__half2*)&X[row * XS + A + e2] = packed[(size_t)(g0w + gi) * 64 + lane];
    }
  }
  __syncthreads();

  // Epilogue: Y[128x64] = X[128x128] @ Wcat; tiles t = w and w+4.
  // A-frag A[m=lane&15][k=quad*8+j]; B-frag B[k=quad*8+j][n=lane&15];
  // C/D: col=lane&15, row=quad*4+reg. (Verified in R4/R6/R7/R8.)
  const int quad = lane >> 4, mn = lane & 15;
#pragma unroll
  for (int jt = 0; jt < 2; ++jt) {
    const int t = w + 4 * jt;
    f32x4 ac[4] = {{0.f, 0.f, 0.f, 0.f}, {0.f, 0.f, 0.f, 0.f},
                   {0.f, 0.f, 0.f, 0.f}, {0.f, 0.f, 0.f, 0.f}};
#pragma unroll
    for (int kt = 0; kt < 4; ++kt) {
      const int ko = kt * 32 + quad * 8;
      const f16x8 a = *(const f16x8*)&X[(t * 16 + mn) * XS + ko];
#pragma unroll
      for (int nt = 0; nt < 4; ++nt) {
        const f16x8 bfr = *(const f16x8*)&WTg[(nt * 16 + mn) * 128 + ko];
        ac[nt] = __builtin_amdgcn_mfma_f32_16x16x32_f16(a, bfr, ac[nt], 0, 0, 0);
      }
    }
#pragma unroll
    for (int nt = 0; nt < 4; ++nt) {
      const int col = nt * 16 + mn;
      const float bv = bb[col];
#pragma unroll
      for (int rg = 0; rg < 4; ++rg) {
        const int r = quad * 4 + rg;               // row within tile
        const int bt = t >> 2;                     // batch
        const int g = blockIdx.x * GPB + (t & 3) * 16 + r;
        if (g < G) y[((size_t)bt * G + g) * 64 + col] = ac[nt][rg] + bv;
      }
    }
  }
}

extern "C" void kernel_launch(void* const* d_in, const int* in_sizes, int n_in,
                              void* d_out, int out_size, void* d_ws, size_t ws_size,
                              hipStream_t stream) {
  const float* out = (const float*)d_in[0];
  const int*   nbr = (const int*)d_in[1];
  const float* W2  = (const float*)d_in[2];
  const float* b2  = (const float*)d_in[3];
  const float* W3  = (const float*)d_in[4];
  const float* b3  = (const float*)d_in[5];
  float* y = (float*)d_out;
  const int G = in_sizes[1] / K;
  const int Gpad = (G + 63) & ~63;   // 64-aligned rows for aligned s_loads

  // ws: packed (G+1)*64 half2 | sortedT K*Gpad int | WTg 128*64 half | bb 64 f32
  __half2* packed = (__half2*)d_ws;
  const size_t pbytes = (size_t)(G + 1) * 64 * sizeof(__half2);
  int* sortedT = (int*)((char*)d_ws + pbytes);
  __half* WTg = (__half*)((char*)sortedT + (size_t)K * Gpad * sizeof(int));
  float* bbp = (float*)(WTg + 128 * 64);

  const int nPack = ((G + 1) * 64 + 255) / 256;
  pack_kernel<<<nPack, 256, 0, stream>>>((const float2*)out, W2, b2, W3, b3,
                                         packed, WTg, bbp, G, nPack);

  sort_kernel<<<(G + 63) / 64, 64, 0, stream>>>(nbr, sortedT, G, Gpad);

  const int blocks = (G + GPB - 1) / GPB;
  fused_kernel<<<blocks, 256, 0, stream>>>(packed, sortedT, WTg, bbp, y, G, Gpad);
}